// Round 15
// baseline (89.477 us; speedup 1.0000x reference)
//
#include <hip/hip_runtime.h>

// TSA_24936580121000 — fused temporal self-attention, MI355X gfx950. Round 15.
// = Round 14 (84us) with the spill surgically removed:
//  (1) #pragma unroll 1 on the pair loop — R14's plain `for` was unrolled and
//      both pairs' register sets interleaved (same failure mode as R12's
//      r-loop) -> VGPR 128 + 12MB spill writes + 5MB reloads.
//  (2) pre[8] residual pre-issue dropped (-32 transient VGPRs at the peak).
//  (3) P5 = R13's exact clean form.
// Everything else unchanged: WT=32/128B pieces, W3 fragment-contiguous weights
// shared across a position pair, wave-private qk, out-into-dead-slot, 2
// barriers, XOR-swizzles, XCD-chunked block swizzle.

#define C_  128
#define T_  16
#define H_  64
#define W_  64
#define HW_ (H_*W_)
#define CO_ 160          // 16 q + 16 k + 128 v
#define WT_ 32           // w positions per block
#define NBLK 512         // 4 b * 64 h * 2 wtiles
#define THW (T_*H_*W_)

typedef float  f32x4  __attribute__((ext_vector_type(4)));
typedef short  bf16x4 __attribute__((ext_vector_type(4)));
typedef short  bf16x8 __attribute__((ext_vector_type(8)));

__device__ __forceinline__ unsigned short f2bf(float f) {
    union { float f; unsigned u; } v; v.f = f;
    unsigned r = v.u + 0x7fffu + ((v.u >> 16) & 1u);   // RNE
    return (unsigned short)(r >> 16);
}
__device__ __forceinline__ float bf2f(unsigned short s) {
    union { unsigned u; float f; } v; v.u = ((unsigned)s) << 16;
    return v.f;
}

// -------- prepack: W3 fragment-contiguous bf16 weights + biases ----------------
// W3[((nt*4+ks)*64 + gp*16 + lr)*8 + j] = W[nt*16 + lr][ks*32 + gp*8 + j]
__global__ __launch_bounds__(256) void tsa_prepack(
        const float* __restrict__ qw, const float* __restrict__ qb,
        const float* __restrict__ kw, const float* __restrict__ kb,
        const float* __restrict__ vw, const float* __restrict__ vb,
        unsigned short* __restrict__ W2, float* __restrict__ b2,
        unsigned short* __restrict__ W3) {
    int i = blockIdx.x * 256 + threadIdx.x;      // 80*256 == 20480 == 160*128
    int o = i >> 7, c = i & 127;
    float v = (o < 16) ? qw[o * C_ + c] : (o < 32) ? kw[(o - 16) * C_ + c]
                                                   : vw[(o - 32) * C_ + c];
    unsigned short u = f2bf(v);
    W2[i] = u;
    int nt = o >> 4, lr = o & 15, ks = c >> 5, gp = (c >> 3) & 3, j = c & 7;
    W3[(((nt * 4 + ks) * 64) + gp * 16 + lr) * 8 + j] = u;
    if (i < CO_) b2[i] = (i < 16) ? qb[i] : (i < 32) ? kb[i - 16] : vb[i - 32];
}

// ---------------- LDS geometry (shorts) ----------------------------------------
// stage/out (time-shared PER SLOT): [pos=32][t=16][c=128 swz] pos-stride 2184,
//   t-stride 136. c stored XOR-swizzled: loc = c ^ ((pos>>2)<<3).
// qkscr: wave-private [wv=8][qk=2][t=16][o-stride 20]  (no barrier needed)
// bias:  f32[160]
#define PS 2184
#define TS 136
#define IDX_X(pos, t, c)   ((pos) * PS + (t) * TS + (c))
#define QOFF 69888
#define QIDX(wv, qk, t, o) (QOFF + (wv) * 640 + (qk) * 320 + (t) * 20 + (o))
#define BIAS_OFF 75008
#define BUF_SH 75328          // 150656 B <= 160 KiB -> 1 block/CU

// ---------------- main fused kernel --------------------------------------------
__global__ __launch_bounds__(512) void tsa_main(
        const float* __restrict__ x, const unsigned short* __restrict__ W3,
        const float* __restrict__ b2, const float* __restrict__ gamma,
        float* __restrict__ y) {

    __shared__ __align__(16) unsigned short buf[BUF_SH];
    float* bias_lds = (float*)&buf[BIAS_OFF];

    // XCD-chunked swizzle (nwg=512 % 8 == 0)
    int bid  = blockIdx.x;
    int work = (bid & 7) * (NBLK / 8) + (bid >> 3);
    int bh = work >> 1;
    int wt = work & 1;
    int b  = bh >> 6, h = bh & 63;
    int w0 = wt * WT_;

    const size_t base = (size_t)b * C_ * THW + (size_t)h * W_ + w0;
    const float* xb = x + base;
    float*       yb = y + base;

    const int tid  = threadIdx.x;
    const int lane = tid & 63;
    const int seg  = tid & 7;         // 16B segment of the 128B w-row
    const int cs0  = tid >> 3;        // channel 0..63 (+64 on second half)
    const float g  = gamma[0];

    const int wv  = tid >> 6;         // wave 0..7 -> positions wv*4 .. wv*4+3
    const int lr  = tid & 15;
    const int grp = (tid & 63) >> 4;

    if (tid < CO_) bias_lds[tid] = b2[tid];

    // ---- P1: stage x tile -> bf16 LDS [pos][t][c-swz]; 128B read pieces -----
    // SERIAL r-loop: one 8-deep batch in flight at a time.
    #pragma unroll 1
    for (int r = 0; r < 2; ++r) {
        const int cs  = cs0 + 64 * r;
        const int loc = cs ^ (seg << 3);
        const float* xcol = xb + (size_t)cs * THW + seg * 4;
        f32x4 xa[8];
        #pragma unroll
        for (int t = 0; t < 8; ++t) xa[t] = *(const f32x4*)(xcol + t * HW_);
        #pragma unroll
        for (int t = 0; t < 8; ++t)
            #pragma unroll
            for (int e = 0; e < 4; ++e)
                buf[IDX_X(seg * 4 + e, t, loc)] = f2bf(xa[t][e]);
        #pragma unroll
        for (int t = 0; t < 8; ++t) xa[t] = *(const f32x4*)(xcol + (t + 8) * HW_);
        #pragma unroll
        for (int t = 0; t < 8; ++t)
            #pragma unroll
            for (int e = 0; e < 4; ++e)
                buf[IDX_X(seg * 4 + e, t + 8, loc)] = f2bf(xa[t][e]);
    }
    __syncthreads();   // B1 (one of only two barriers)

    // ---- per-wave: 2 PAIRS of positions; wf fragments shared within a pair ---
    // SERIAL pair loop: pairs must NOT be interleaved (register-peak control).
    const int swz = wv << 3;          // pos>>2 == wv for this wave's positions
    #pragma unroll 1
    for (int pr = 0; pr < 2; ++pr) {
        const int posA = wv * 4 + pr * 2;
        const int posB = posA + 1;

        // afrag preload for both positions (slots dead afterwards)
        bf16x8 afA[4], afB[4];
        #pragma unroll
        for (int ks = 0; ks < 4; ++ks) {
            afA[ks] = *(const bf16x8*)&buf[IDX_X(posA, lr, (ks * 32 + grp * 8) ^ swz)];
            afB[ks] = *(const bf16x8*)&buf[IDX_X(posB, lr, (ks * 32 + grp * 8) ^ swz)];
        }

        // qkv projection: ONE wf load feeds TWO MFMAs (A and B)
        bf16x4 vreg[2][8];
        bf16x4 qkB[2];                // pos-B q/k parked in regs during A's P3
        #pragma unroll
        for (int nt = 0; nt < 10; ++nt) {
            f32x4 acc0 = (f32x4){0.f, 0.f, 0.f, 0.f};
            f32x4 acc1 = (f32x4){0.f, 0.f, 0.f, 0.f};
            #pragma unroll
            for (int ks = 0; ks < 4; ++ks) {
                bf16x8 wf = *(const bf16x8*)&W3[(((nt * 4 + ks) * 64) + lane) * 8];
                acc0 = __builtin_amdgcn_mfma_f32_16x16x32_bf16(afA[ks], wf, acc0, 0, 0, 0);
                acc1 = __builtin_amdgcn_mfma_f32_16x16x32_bf16(afB[ks], wf, acc1, 0, 0, 0);
            }
            float bv = bias_lds[nt * 16 + lr];
            if (nt < 2) {
                #pragma unroll
                for (int rr = 0; rr < 4; ++rr)
                    buf[QIDX(wv, nt, grp * 4 + rr, lr)] = f2bf(acc0[rr] + bv);
                bf16x4 pk;
                #pragma unroll
                for (int rr = 0; rr < 4; ++rr) pk[rr] = (short)f2bf(acc1[rr] + bv);
                qkB[nt] = pk;
            } else {
                bf16x4 pA, pB;
                #pragma unroll
                for (int rr = 0; rr < 4; ++rr) {
                    pA[rr] = (short)f2bf(acc0[rr] + bv);
                    pB[rr] = (short)f2bf(acc1[rr] + bv);
                }
                vreg[0][nt - 2] = pA;
                vreg[1][nt - 2] = pB;
            }
        }

        // ---- P3 for A, then park->slot swap, then P3 for B -------------------
        #pragma unroll
        for (int p = 0; p < 2; ++p) {
            const int pos = p ? posB : posA;
            if (p) {   // overwrite slot with B's q/k (A's reads already done)
                #pragma unroll
                for (int rr = 0; rr < 4; ++rr) {
                    buf[QIDX(wv, 0, grp * 4 + rr, lr)] = (unsigned short)qkB[0][rr];
                    buf[QIDX(wv, 1, grp * 4 + rr, lr)] = (unsigned short)qkB[1][rr];
                }
            }
            bf16x4 kf = *(const bf16x4*)&buf[QIDX(wv, 1, lr, grp * 4)];
            bf16x4 qf = *(const bf16x4*)&buf[QIDX(wv, 0, lr, grp * 4)];
            f32x4 s = (f32x4){0.f, 0.f, 0.f, 0.f};
            s = __builtin_amdgcn_mfma_f32_16x16x16bf16_1k(kf, qf, s, 0, 0, 0);
            float mx = fmaxf(fmaxf(s[0], s[1]), fmaxf(s[2], s[3]));
            mx = fmaxf(mx, __shfl_xor(mx, 16));
            mx = fmaxf(mx, __shfl_xor(mx, 32));
            float e0 = __expf(s[0] - mx), e1 = __expf(s[1] - mx);
            float e2 = __expf(s[2] - mx), e3 = __expf(s[3] - mx);
            float sm = e0 + e1 + e2 + e3;
            sm += __shfl_xor(sm, 16);
            sm += __shfl_xor(sm, 32);
            float inv = 1.0f / sm;
            bf16x4 pf;
            pf[0] = (short)f2bf(e0 * inv); pf[1] = (short)f2bf(e1 * inv);
            pf[2] = (short)f2bf(e2 * inv); pf[3] = (short)f2bf(e3 * inv);
            #pragma unroll
            for (int ct = 0; ct < 8; ++ct) {
                f32x4 z = (f32x4){0.f, 0.f, 0.f, 0.f};
                z = __builtin_amdgcn_mfma_f32_16x16x16bf16_1k(vreg[p][ct], pf, z, 0, 0, 0);
                bf16x4 ob;
                #pragma unroll
                for (int rr = 0; rr < 4; ++rr) ob[rr] = (short)f2bf(z[rr]);
                *(bf16x4*)&buf[IDX_X(pos, lr, (ct * 16 + grp * 4) ^ swz)] = ob;
            }
        }
    }
    __syncthreads();   // B2: all outT slots visible

    // ---- P5: y = gamma*out + x (exact fp32 residual); 128B pieces -----------
    // SERIAL r-loop + 8-deep halves: max 32 transient VGPRs (R13's clean form).
    #pragma unroll 1
    for (int r = 0; r < 2; ++r) {
        const int cs  = cs0 + 64 * r;
        const int loc = cs ^ (seg << 3);   // matches writer: pos>>2 == seg here
        const float* xrow = xb + (size_t)cs * THW + seg * 4;
        float*       yrow = yb + (size_t)cs * THW + seg * 4;
        #pragma unroll
        for (int half = 0; half < 2; ++half) {
            const int t0 = half * 8;
            f32x4 xa[8];
            #pragma unroll
            for (int t = 0; t < 8; ++t) xa[t] = *(const f32x4*)(xrow + (t0 + t) * HW_);
            #pragma unroll
            for (int t = 0; t < 8; ++t) {
                f32x4 rv;
                #pragma unroll
                for (int e = 0; e < 4; ++e)
                    rv[e] = fmaf(g, bf2f(buf[IDX_X(seg * 4 + e, t0 + t, loc)]), xa[t][e]);
                *(f32x4*)(yrow + (t0 + t) * HW_) = rv;
            }
        }
    }
}

// ---------------- launch --------------------------------------------------------
extern "C" void kernel_launch(void* const* d_in, const int* in_sizes, int n_in,
                              void* d_out, int out_size, void* d_ws, size_t ws_size,
                              hipStream_t stream) {
    const float* x  = (const float*)d_in[0];
    const float* qw = (const float*)d_in[1];
    const float* qb = (const float*)d_in[2];
    const float* kw = (const float*)d_in[3];
    const float* kb = (const float*)d_in[4];
    const float* vw = (const float*)d_in[5];
    const float* vb = (const float*)d_in[6];
    const float* gm = (const float*)d_in[7];
    float* y = (float*)d_out;

    unsigned short* W2 = (unsigned short*)d_ws;                        // 40960 B
    float*          b2 = (float*)((char*)d_ws + 40960);                //   640 B
    unsigned short* W3 = (unsigned short*)((char*)d_ws + 41600);       // 40960 B

    tsa_prepack<<<80, 256, 0, stream>>>(qw, qb, kw, kb, vw, vb, W2, b2, W3);
    tsa_main<<<NBLK, 512, 0, stream>>>(x, W3, b2, gm, y);
}

// Round 16
// 84.257 us; speedup vs baseline: 1.0620x; 1.0620x over previous
//
#include <hip/hip_runtime.h>

// TSA_24936580121000 — fused temporal self-attention, MI355X gfx950. Round 16.
// EXACT REVERT to Round 14 (best: 84.0us, 279 MB @ 3.32 TB/s = 96% of the
// measured 128B-scatter-grain ceiling). R15's two "fixes" (serial pair loop,
// dropped pre-issue) both regressed: the paired-P2 spill (12MB, ~3.5us) buys
// more overlap than it costs. Operating point:
//  - WT=32: all global pieces 128B contiguous (the grain that sets the rate)
//  - W3 fragment-contiguous weights, one wf load feeds a position PAIR
//  - wave-private qk scratch, outT into dead stage slot, 2 barriers
//  - XOR-swizzled stage LDS, XCD-chunked block swizzle
//  - P5 residual re-read exact fp32 (L2/L3-hot), first batch pre-issued

#define C_  128
#define T_  16
#define H_  64
#define W_  64
#define HW_ (H_*W_)
#define CO_ 160          // 16 q + 16 k + 128 v
#define WT_ 32           // w positions per block
#define NBLK 512         // 4 b * 64 h * 2 wtiles
#define THW (T_*H_*W_)

typedef float  f32x4  __attribute__((ext_vector_type(4)));
typedef short  bf16x4 __attribute__((ext_vector_type(4)));
typedef short  bf16x8 __attribute__((ext_vector_type(8)));

__device__ __forceinline__ unsigned short f2bf(float f) {
    union { float f; unsigned u; } v; v.f = f;
    unsigned r = v.u + 0x7fffu + ((v.u >> 16) & 1u);   // RNE
    return (unsigned short)(r >> 16);
}
__device__ __forceinline__ float bf2f(unsigned short s) {
    union { unsigned u; float f; } v; v.u = ((unsigned)s) << 16;
    return v.f;
}

// -------- prepack: W2[160][128] bf16 + W3 fragment-contiguous + biases --------
// W3[((nt*4+ks)*64 + gp*16 + lr)*8 + j] = W[nt*16 + lr][ks*32 + gp*8 + j]
__global__ __launch_bounds__(256) void tsa_prepack(
        const float* __restrict__ qw, const float* __restrict__ qb,
        const float* __restrict__ kw, const float* __restrict__ kb,
        const float* __restrict__ vw, const float* __restrict__ vb,
        unsigned short* __restrict__ W2, float* __restrict__ b2,
        unsigned short* __restrict__ W3) {
    int i = blockIdx.x * 256 + threadIdx.x;      // 80*256 == 20480 == 160*128
    int o = i >> 7, c = i & 127;
    float v = (o < 16) ? qw[o * C_ + c] : (o < 32) ? kw[(o - 16) * C_ + c]
                                                   : vw[(o - 32) * C_ + c];
    unsigned short u = f2bf(v);
    W2[i] = u;
    int nt = o >> 4, lr = o & 15, ks = c >> 5, gp = (c >> 3) & 3, j = c & 7;
    W3[(((nt * 4 + ks) * 64) + gp * 16 + lr) * 8 + j] = u;
    if (i < CO_) b2[i] = (i < 16) ? qb[i] : (i < 32) ? kb[i - 16] : vb[i - 32];
}

// ---------------- LDS geometry (shorts) ----------------------------------------
// stage/out (time-shared PER SLOT): [pos=32][t=16][c=128 swz] pos-stride 2184,
//   t-stride 136. c stored XOR-swizzled: loc = c ^ ((pos>>2)<<3).
// qkscr: wave-private [wv=8][qk=2][t=16][o-stride 20]  (no barrier needed)
// bias:  f32[160]
#define PS 2184
#define TS 136
#define IDX_X(pos, t, c)   ((pos) * PS + (t) * TS + (c))
#define QOFF 69888
#define QIDX(wv, qk, t, o) (QOFF + (wv) * 640 + (qk) * 320 + (t) * 20 + (o))
#define BIAS_OFF 75008
#define BUF_SH 75328          // 150656 B <= 160 KiB -> 1 block/CU

// ---------------- main fused kernel --------------------------------------------
__global__ __launch_bounds__(512) void tsa_main(
        const float* __restrict__ x, const unsigned short* __restrict__ W3,
        const float* __restrict__ b2, const float* __restrict__ gamma,
        float* __restrict__ y) {

    __shared__ __align__(16) unsigned short buf[BUF_SH];
    float* bias_lds = (float*)&buf[BIAS_OFF];

    // XCD-chunked swizzle (nwg=512 % 8 == 0)
    int bid  = blockIdx.x;
    int work = (bid & 7) * (NBLK / 8) + (bid >> 3);
    int bh = work >> 1;
    int wt = work & 1;
    int b  = bh >> 6, h = bh & 63;
    int w0 = wt * WT_;

    const size_t base = (size_t)b * C_ * THW + (size_t)h * W_ + w0;
    const float* xb = x + base;
    float*       yb = y + base;

    const int tid  = threadIdx.x;
    const int lane = tid & 63;
    const int seg  = tid & 7;         // 16B segment of the 128B w-row
    const int cs0  = tid >> 3;        // channel 0..63 (+64 on second half)
    const float g  = gamma[0];

    const int wv  = tid >> 6;         // wave 0..7 -> positions wv*4 .. wv*4+3
    const int lr  = tid & 15;
    const int grp = (tid & 63) >> 4;

    if (tid < CO_) bias_lds[tid] = b2[tid];

    // ---- P1: stage x tile -> bf16 LDS [pos][t][c-swz]; 128B read pieces -----
    // SERIAL r-loop: one 8-deep batch in flight at a time.
    for (int r = 0; r < 2; ++r) {
        const int cs  = cs0 + 64 * r;
        const int loc = cs ^ (seg << 3);
        const float* xcol = xb + (size_t)cs * THW + seg * 4;
        f32x4 xa[8];
        #pragma unroll
        for (int t = 0; t < 8; ++t) xa[t] = *(const f32x4*)(xcol + t * HW_);
        #pragma unroll
        for (int t = 0; t < 8; ++t)
            #pragma unroll
            for (int e = 0; e < 4; ++e)
                buf[IDX_X(seg * 4 + e, t, loc)] = f2bf(xa[t][e]);
        #pragma unroll
        for (int t = 0; t < 8; ++t) xa[t] = *(const f32x4*)(xcol + (t + 8) * HW_);
        #pragma unroll
        for (int t = 0; t < 8; ++t)
            #pragma unroll
            for (int e = 0; e < 4; ++e)
                buf[IDX_X(seg * 4 + e, t + 8, loc)] = f2bf(xa[t][e]);
    }
    __syncthreads();   // B1 (one of only two barriers)

    // ---- per-wave: 2 PAIRS of positions; wf fragments shared within a pair ---
    const int swz = wv << 3;          // pos>>2 == wv for this wave's positions
    for (int pr = 0; pr < 2; ++pr) {
        const int posA = wv * 4 + pr * 2;
        const int posB = posA + 1;

        // afrag preload for both positions (slots dead afterwards)
        bf16x8 afA[4], afB[4];
        #pragma unroll
        for (int ks = 0; ks < 4; ++ks) {
            afA[ks] = *(const bf16x8*)&buf[IDX_X(posA, lr, (ks * 32 + grp * 8) ^ swz)];
            afB[ks] = *(const bf16x8*)&buf[IDX_X(posB, lr, (ks * 32 + grp * 8) ^ swz)];
        }

        // qkv projection: ONE wf load feeds TWO MFMAs (A and B)
        bf16x4 vreg[2][8];
        bf16x4 qkB[2];                // pos-B q/k parked in regs during A's P3
        #pragma unroll
        for (int nt = 0; nt < 10; ++nt) {
            f32x4 acc0 = (f32x4){0.f, 0.f, 0.f, 0.f};
            f32x4 acc1 = (f32x4){0.f, 0.f, 0.f, 0.f};
            #pragma unroll
            for (int ks = 0; ks < 4; ++ks) {
                bf16x8 wf = *(const bf16x8*)&W3[(((nt * 4 + ks) * 64) + lane) * 8];
                acc0 = __builtin_amdgcn_mfma_f32_16x16x32_bf16(afA[ks], wf, acc0, 0, 0, 0);
                acc1 = __builtin_amdgcn_mfma_f32_16x16x32_bf16(afB[ks], wf, acc1, 0, 0, 0);
            }
            float bv = bias_lds[nt * 16 + lr];
            if (nt < 2) {
                #pragma unroll
                for (int rr = 0; rr < 4; ++rr)
                    buf[QIDX(wv, nt, grp * 4 + rr, lr)] = f2bf(acc0[rr] + bv);
                bf16x4 pk;
                #pragma unroll
                for (int rr = 0; rr < 4; ++rr) pk[rr] = (short)f2bf(acc1[rr] + bv);
                qkB[nt] = pk;
            } else {
                bf16x4 pA, pB;
                #pragma unroll
                for (int rr = 0; rr < 4; ++rr) {
                    pA[rr] = (short)f2bf(acc0[rr] + bv);
                    pB[rr] = (short)f2bf(acc1[rr] + bv);
                }
                vreg[0][nt - 2] = pA;
                vreg[1][nt - 2] = pB;
            }
        }

        // ---- P3 for A, then park->slot swap, then P3 for B -------------------
        #pragma unroll
        for (int p = 0; p < 2; ++p) {
            const int pos = p ? posB : posA;
            if (p) {   // overwrite slot with B's q/k (A's reads already done)
                #pragma unroll
                for (int rr = 0; rr < 4; ++rr) {
                    buf[QIDX(wv, 0, grp * 4 + rr, lr)] = (unsigned short)qkB[0][rr];
                    buf[QIDX(wv, 1, grp * 4 + rr, lr)] = (unsigned short)qkB[1][rr];
                }
            }
            bf16x4 kf = *(const bf16x4*)&buf[QIDX(wv, 1, lr, grp * 4)];
            bf16x4 qf = *(const bf16x4*)&buf[QIDX(wv, 0, lr, grp * 4)];
            f32x4 s = (f32x4){0.f, 0.f, 0.f, 0.f};
            s = __builtin_amdgcn_mfma_f32_16x16x16bf16_1k(kf, qf, s, 0, 0, 0);
            float mx = fmaxf(fmaxf(s[0], s[1]), fmaxf(s[2], s[3]));
            mx = fmaxf(mx, __shfl_xor(mx, 16));
            mx = fmaxf(mx, __shfl_xor(mx, 32));
            float e0 = __expf(s[0] - mx), e1 = __expf(s[1] - mx);
            float e2 = __expf(s[2] - mx), e3 = __expf(s[3] - mx);
            float sm = e0 + e1 + e2 + e3;
            sm += __shfl_xor(sm, 16);
            sm += __shfl_xor(sm, 32);
            float inv = 1.0f / sm;
            bf16x4 pf;
            pf[0] = (short)f2bf(e0 * inv); pf[1] = (short)f2bf(e1 * inv);
            pf[2] = (short)f2bf(e2 * inv); pf[3] = (short)f2bf(e3 * inv);
            #pragma unroll
            for (int ct = 0; ct < 8; ++ct) {
                f32x4 z = (f32x4){0.f, 0.f, 0.f, 0.f};
                z = __builtin_amdgcn_mfma_f32_16x16x16bf16_1k(vreg[p][ct], pf, z, 0, 0, 0);
                bf16x4 ob;
                #pragma unroll
                for (int rr = 0; rr < 4; ++rr) ob[rr] = (short)f2bf(z[rr]);
                *(bf16x4*)&buf[IDX_X(pos, lr, (ct * 16 + grp * 4) ^ swz)] = ob;
            }
        }
    }

    // ---- pre-issue first residual batch (r=0, t 0..7), then B2 ---------------
    const float* xrow0 = xb + (size_t)cs0 * THW + seg * 4;
    f32x4 pre[8];
    #pragma unroll
    for (int t = 0; t < 8; ++t) pre[t] = *(const f32x4*)(xrow0 + t * HW_);

    __syncthreads();   // B2: all outT slots visible

    // ---- P5: y = gamma*out + x (exact fp32 residual); 128B pieces ------------
    for (int r = 0; r < 2; ++r) {
        const int cs  = cs0 + 64 * r;
        const int loc = cs ^ (seg << 3);   // matches writer: pos>>2 == seg here
        const float* xrow = xb + (size_t)cs * THW + seg * 4;
        float*       yrow = yb + (size_t)cs * THW + seg * 4;
        #pragma unroll
        for (int half = 0; half < 2; ++half) {
            const int t0 = half * 8;
            f32x4 xa[8];
            if (r == 0 && half == 0) {
                #pragma unroll
                for (int t = 0; t < 8; ++t) xa[t] = pre[t];
            } else {
                #pragma unroll
                for (int t = 0; t < 8; ++t) xa[t] = *(const f32x4*)(xrow + (t0 + t) * HW_);
            }
            #pragma unroll
            for (int t = 0; t < 8; ++t) {
                f32x4 rv;
                #pragma unroll
                for (int e = 0; e < 4; ++e)
                    rv[e] = fmaf(g, bf2f(buf[IDX_X(seg * 4 + e, t0 + t, loc)]), xa[t][e]);
                *(f32x4*)(yrow + (t0 + t) * HW_) = rv;
            }
        }
    }
}

// ---------------- launch --------------------------------------------------------
extern "C" void kernel_launch(void* const* d_in, const int* in_sizes, int n_in,
                              void* d_out, int out_size, void* d_ws, size_t ws_size,
                              hipStream_t stream) {
    const float* x  = (const float*)d_in[0];
    const float* qw = (const float*)d_in[1];
    const float* qb = (const float*)d_in[2];
    const float* kw = (const float*)d_in[3];
    const float* kb = (const float*)d_in[4];
    const float* vw = (const float*)d_in[5];
    const float* vb = (const float*)d_in[6];
    const float* gm = (const float*)d_in[7];
    float* y = (float*)d_out;

    unsigned short* W2 = (unsigned short*)d_ws;                        // 40960 B
    float*          b2 = (float*)((char*)d_ws + 40960);                //   640 B
    unsigned short* W3 = (unsigned short*)((char*)d_ws + 41600);       // 40960 B

    tsa_prepack<<<80, 256, 0, stream>>>(qw, qb, kw, kb, vw, vb, W2, b2, W3);
    tsa_main<<<NBLK, 512, 0, stream>>>(x, W3, b2, gm, y);
}